// Round 8
// baseline (418.603 us; speedup 1.0000x reference)
//
#include <hip/hip_runtime.h>

#define N_NODES_C 100000
#define N_EDGES_C 1200000
#define NUM_GRAPHS_C 64
#define D_C 64
#define CAP_C 64
#define BN_EPS_C 1e-5f

typedef unsigned short u16;
typedef unsigned int u32;

using frag_ab = __attribute__((ext_vector_type(8))) short;  // 8 bf16 (4 VGPRs)
using f32x4   = __attribute__((ext_vector_type(4))) float;

__device__ __forceinline__ u16 f2bf(float f) {  // RTNE
    u32 x = __float_as_uint(f);
    x += 0x7fffu + ((x >> 16) & 1u);
    return (u16)(x >> 16);
}
__device__ __forceinline__ float bf2f(u16 u) {
    return __uint_as_float(((u32)u) << 16);
}

// ------------------- prep: x -> bf16, W1/W2 -> bf16 [n][k] ----------------
__global__ void k_prep(const float* __restrict__ x,
                       const float* __restrict__ W1, const float* __restrict__ W2,
                       u16* __restrict__ Xb, u16* __restrict__ Wb1,
                       u16* __restrict__ Wb2) {
    int i = blockIdx.x * 256 + threadIdx.x;
    int base = i * 4;
    if (base < N_NODES_C * D_C) {
        float4 f = *(const float4*)(x + base);
        ushort4 o;
        o.x = f2bf(f.x); o.y = f2bf(f.y); o.z = f2bf(f.z); o.w = f2bf(f.w);
        *(ushort4*)(Xb + base) = o;
    }
    if (i < 4096) {  // W[k][n] -> Wb[n][k]
        int n = i >> 6, k = i & 63;
        Wb1[i] = f2bf(W1[k * 64 + n]);
        Wb2[i] = f2bf(W2[k * 64 + n]);
    }
}

// ------------------- bucket scatter (CSR-free) ----------------------------
// dst ~ Uniform(100K), E=1.2M -> Poisson(12); P(deg>64) ~ 1e-28. Clamp for
// memory safety only. 4 edges per thread, vectorized index reads.
__global__ void k_scatter(const int* __restrict__ src, const int* __restrict__ dst,
                          int* __restrict__ cnt, int* __restrict__ col) {
    int i = blockIdx.x * blockDim.x + threadIdx.x;
    int e0 = i * 4;
    if (e0 + 3 < N_EDGES_C) {
        int4 s4 = *(const int4*)(src + e0);
        int4 d4 = *(const int4*)(dst + e0);
        int ss[4] = {s4.x, s4.y, s4.z, s4.w};
        int dd[4] = {d4.x, d4.y, d4.z, d4.w};
#pragma unroll
        for (int k = 0; k < 4; ++k) {
            int pos = atomicAdd(&cnt[dd[k]], 1);
            if (pos < CAP_C) col[(size_t)dd[k] * CAP_C + pos] = ss[k];
        }
    } else {
        for (int e = e0; e < N_EDGES_C; ++e) {
            int s = src[e], d = dst[e];
            int pos = atomicAdd(&cnt[d], 1);
            if (pos < CAP_C) col[(size_t)d * CAP_C + pos] = s;
        }
    }
}

// ------------------- GEMM via MFMA 16x16x32 bf16 --------------------------
// One wave per 16-row strip. B fragments preloaded (constant across strips).
// Epilogue folds dinv[row] = rsqrt(cnt[row]+1).
__global__ void __launch_bounds__(256) k_gemm_mfma(
        const u16* __restrict__ Xb, const u16* __restrict__ Wb,
        const int* __restrict__ cnt, u16* __restrict__ T) {
    int lane = threadIdx.x & 63;
    int q = lane >> 4, ln = lane & 15;
    int wave = blockIdx.x * 4 + (threadIdx.x >> 6);
    int nwaves = gridDim.x * 4;
    frag_ab bfr[4][2];
#pragma unroll
    for (int nt = 0; nt < 4; ++nt)
#pragma unroll
        for (int kh = 0; kh < 2; ++kh)
            bfr[nt][kh] = *(const frag_ab*)(Wb + (nt * 16 + ln) * 64 + kh * 32 + q * 8);
    const int nstrips = N_NODES_C / 16;
    for (int s = wave; s < nstrips; s += nwaves) {
        int r0 = s * 16;
        frag_ab a0 = *(const frag_ab*)(Xb + (size_t)(r0 + ln) * 64 + q * 8);
        frag_ab a1 = *(const frag_ab*)(Xb + (size_t)(r0 + ln) * 64 + 32 + q * 8);
        f32x4 acc[4];
#pragma unroll
        for (int nt = 0; nt < 4; ++nt) {
            acc[nt] = (f32x4){0.f, 0.f, 0.f, 0.f};
            acc[nt] = __builtin_amdgcn_mfma_f32_16x16x32_bf16(a0, bfr[nt][0], acc[nt], 0, 0, 0);
            acc[nt] = __builtin_amdgcn_mfma_f32_16x16x32_bf16(a1, bfr[nt][1], acc[nt], 0, 0, 0);
        }
        float di[4];
#pragma unroll
        for (int reg = 0; reg < 4; ++reg)
            di[reg] = rsqrtf((float)(cnt[r0 + q * 4 + reg] + 1));
#pragma unroll
        for (int nt = 0; nt < 4; ++nt)
#pragma unroll
            for (int reg = 0; reg < 4; ++reg)
                T[(size_t)(r0 + q * 4 + reg) * 64 + nt * 16 + ln] =
                    f2bf(acc[nt][reg] * di[reg]);
    }
}

// ------------------- gather (pair-fused over buckets) ---------------------
// R5-proven pair shape + R7 buckets. Wave owns a CONTIGUOUS chunk of node
// pairs; per pair the two buckets form one logical edge stream of
// degA+degB edges, routed to accA/accB by boundary compare. 8-deep batches
// (VGPR~20 shape the compiler pipelines; 16-deep serializes — R6 lesson).
// Invalid slots masked to the hot self row BEFORE use (ws is 0xAA-poisoned).
// POOL: run-length pooling — contiguous nodes mean ~1 graph-boundary per
// wave chunk -> ~1 atomic flush per lane per wave (vs 1 per node in R7).
template <bool POOL>
__device__ __forceinline__ void gather_body(
        const u16* __restrict__ T, const int* __restrict__ col,
        const int* __restrict__ cnt,
        const float* __restrict__ b, const float* __restrict__ g,
        const float* __restrict__ be, const float* __restrict__ m,
        const float* __restrict__ v, const int* __restrict__ batch,
        u16* __restrict__ Ab, float* __restrict__ pooled) {
    int lane = threadIdx.x & 63;
    int wave = blockIdx.x * 4 + (threadIdx.x >> 6);
    int nwaves = gridDim.x * 4;
    float sc = g[lane] * rsqrtf(v[lane] + BN_EPS_C);
    float c0 = (b[lane] - m[lane]) * sc + be[lane];
    const int npairs = N_NODES_C / 2;
    const int chunk = (npairs + nwaves - 1) / nwaves;
    int p0 = wave * chunk;
    int p1 = p0 + chunk; if (p1 > npairs) p1 = npairs;
    float psum = 0.f; int curg = -1;
    for (int p = p0; p < p1; ++p) {
        int rA = __builtin_amdgcn_readfirstlane(p * 2);
        int rB = rA + 1;
        int degA = cnt[rA]; if (degA > CAP_C) degA = CAP_C;
        int degB = cnt[rB]; if (degB > CAP_C) degB = CAP_C;
        int tot = degA + degB;
        const int* cbA = col + (size_t)rA * CAP_C;
        const int* cbB = col + (size_t)rB * CAP_C;
        float accA = bf2f(T[(size_t)rA * 64 + lane]);  // self (dinv in T)
        float accB = bf2f(T[(size_t)rB * 64 + lane]);
        for (int j = 0; j < tot; j += 8) {
            int idx[8];
#pragma unroll
            for (int k = 0; k < 8; ++k) {
                int jj = j + k;
                bool valid = jj < tot;
                bool isB = jj >= degA;
                const int* cb = isB ? cbB : cbA;
                int o = isB ? (jj - degA) : jj;
                int c = cb[valid ? o : 0];   // in-bounds addr; value masked next
                idx[k] = valid ? c : rA;     // tail -> hot self row
            }
            float tv[8];
#pragma unroll
            for (int k = 0; k < 8; ++k)
                tv[k] = bf2f(T[(size_t)idx[k] * 64 + lane]);
#pragma unroll
            for (int k = 0; k < 8; ++k) {
                int jj = j + k;
                accA += (jj < degA) ? tv[k] : 0.f;
                accB += (jj >= degA && jj < tot) ? tv[k] : 0.f;
            }
        }
        float drA = rsqrtf((float)(degA + 1));
        float drB = rsqrtf((float)(degB + 1));
        float valA = fmaxf(fmaf(accA * drA, sc, c0), 0.f);
        float valB = fmaxf(fmaf(accB * drB, sc, c0), 0.f);
        if (POOL) {
            int gA = batch[rA], gB = batch[rB];
            if (gA != curg) {
                if (curg >= 0) atomicAdd(&pooled[curg * 64 + lane], psum);
                curg = gA; psum = 0.f;
            }
            psum += valA;
            if (gB != curg) {
                atomicAdd(&pooled[curg * 64 + lane], psum);
                curg = gB; psum = 0.f;
            }
            psum += valB;
        } else {
            Ab[(size_t)rA * 64 + lane] = f2bf(valA);
            Ab[(size_t)rB * 64 + lane] = f2bf(valB);
        }
    }
    if (POOL && curg >= 0) atomicAdd(&pooled[curg * 64 + lane], psum);
}

__global__ void __launch_bounds__(256) k_gather1(
        const u16* __restrict__ T, const int* __restrict__ col,
        const int* __restrict__ cnt,
        const float* __restrict__ b, const float* __restrict__ g,
        const float* __restrict__ be, const float* __restrict__ m,
        const float* __restrict__ v, u16* __restrict__ Ab) {
    gather_body<false>(T, col, cnt, b, g, be, m, v, nullptr, Ab, nullptr);
}

__global__ void __launch_bounds__(256) k_gather2(
        const u16* __restrict__ T, const int* __restrict__ col,
        const int* __restrict__ cnt,
        const float* __restrict__ b, const float* __restrict__ g,
        const float* __restrict__ be, const float* __restrict__ m,
        const float* __restrict__ v, const int* __restrict__ batch,
        float* __restrict__ pooled) {
    gather_body<true>(T, col, cnt, b, g, be, m, v, batch, nullptr, pooled);
}

// ----------------------------- classifier --------------------------------
__global__ void k_final(const float* __restrict__ pooled, const int* __restrict__ batch,
                        const float* __restrict__ Wc, const float* __restrict__ bc,
                        float* __restrict__ out) {
    __shared__ float sp[64 * 65];
    __shared__ int sub[64];
    int t = threadIdx.x;  // 256 threads
    for (int i = t; i < 4096; i += 256) sp[(i >> 6) * 65 + (i & 63)] = pooled[i];
    if (t < 64) {
        int lo = 0, hi = N_NODES_C;
        while (lo < hi) { int mid = (lo + hi) >> 1; if (batch[mid] > t) hi = mid; else lo = mid + 1; }
        sub[t] = lo;  // first index with batch > t
    }
    __syncthreads();
    if (t < 64) {
        int gi = t;
        int lb = gi ? sub[gi - 1] : 0;
        int cntg = sub[gi] - lb;
        float inv = 1.0f / fmaxf((float)cntg, 1.0f);
        float a0 = 0.f, a1 = 0.f;
#pragma unroll 8
        for (int f = 0; f < 64; ++f) {
            float p = sp[gi * 65 + f];
            a0 = fmaf(p, Wc[f * 2 + 0], a0);
            a1 = fmaf(p, Wc[f * 2 + 1], a1);
        }
        out[gi * 2 + 0] = a0 * inv + bc[0];
        out[gi * 2 + 1] = a1 * inv + bc[1];
    }
}

extern "C" void kernel_launch(void* const* d_in, const int* in_sizes, int n_in,
                              void* d_out, int out_size, void* d_ws, size_t ws_size,
                              hipStream_t stream) {
    const float* x    = (const float*)d_in[0];
    const int*   ei   = (const int*)d_in[1];
    const int*   batch= (const int*)d_in[2];
    const float* W1 = (const float*)d_in[3];
    const float* b1 = (const float*)d_in[4];
    const float* g1 = (const float*)d_in[5];
    const float* be1= (const float*)d_in[6];
    const float* m1 = (const float*)d_in[7];
    const float* v1 = (const float*)d_in[8];
    const float* W2 = (const float*)d_in[9];
    const float* b2 = (const float*)d_in[10];
    const float* g2 = (const float*)d_in[11];
    const float* be2= (const float*)d_in[12];
    const float* m2 = (const float*)d_in[13];
    const float* v2 = (const float*)d_in[14];
    const float* Wc = (const float*)d_in[15];
    const float* bc = (const float*)d_in[16];
    float* out = (float*)d_out;

    char* ws = (char*)d_ws;
    size_t off = 0;
    auto alloc = [&](size_t bytes) {
        size_t o = off;
        off = (off + bytes + 511) & ~(size_t)511;
        return o;
    };
    size_t o_cnt   = alloc((size_t)N_NODES_C * 4);
    size_t o_pool  = alloc((size_t)NUM_GRAPHS_C * D_C * 4);
    size_t zero_bytes = off;  // [cnt | pooled] zeroed each call
    size_t o_col   = alloc((size_t)N_NODES_C * CAP_C * 4);  // 25.6 MB buckets
    size_t o_xb    = alloc((size_t)N_NODES_C * D_C * 2);
    size_t o_wb1   = alloc(4096 * 2);
    size_t o_wb2   = alloc(4096 * 2);
    size_t o_t     = alloc((size_t)N_NODES_C * D_C * 2);  // bf16 (dinv folded)
    size_t o_ab    = alloc((size_t)N_NODES_C * D_C * 2);  // bf16 activations
    (void)ws_size; (void)in_sizes; (void)n_in; (void)out_size;

    int*   cnt    = (int*)(ws + o_cnt);
    float* pooled = (float*)(ws + o_pool);
    int*   col    = (int*)(ws + o_col);
    u16*   Xb     = (u16*)(ws + o_xb);
    u16*   Wb1    = (u16*)(ws + o_wb1);
    u16*   Wb2    = (u16*)(ws + o_wb2);
    u16*   T      = (u16*)(ws + o_t);
    u16*   Ab     = (u16*)(ws + o_ab);

    const int* srcp = ei;
    const int* dstp = ei + N_EDGES_C;

    hipMemsetAsync(ws, 0, zero_bytes, stream);

    int sblocks = (N_EDGES_C / 4 + 255) / 256;          // 4 edges/thread
    int pblocks = (N_NODES_C * D_C / 4 + 255) / 256;    // 6250
    int gblocks = 2048;   // 8192 persistent waves
    int mblocks = 1563;   // 6252 waves: one 16-row strip each
    k_prep<<<pblocks, 256, 0, stream>>>(x, W1, W2, Xb, Wb1, Wb2);
    k_scatter<<<sblocks, 256, 0, stream>>>(srcp, dstp, cnt, col);

    k_gemm_mfma<<<mblocks, 256, 0, stream>>>(Xb, Wb1, cnt, T);
    k_gather1<<<gblocks, 256, 0, stream>>>(T, col, cnt, b1, g1, be1, m1, v1, Ab);
    k_gemm_mfma<<<mblocks, 256, 0, stream>>>(Ab, Wb2, cnt, T);
    k_gather2<<<gblocks, 256, 0, stream>>>(T, col, cnt, b2, g2, be2, m2, v2,
                                           batch, pooled);
    k_final<<<1, 256, 0, stream>>>(pooled, batch, Wc, bc, out);
}

// Round 9
// 403.977 us; speedup vs baseline: 1.0362x; 1.0362x over previous
//
#include <hip/hip_runtime.h>

#define N_NODES_C 100000
#define N_EDGES_C 1200000
#define NUM_GRAPHS_C 64
#define D_C 64
#define CAP_C 64
#define NPASS_C 4
#define BN_EPS_C 1e-5f

typedef unsigned short u16;
typedef unsigned int u32;

using frag_ab = __attribute__((ext_vector_type(8))) short;  // 8 bf16 (4 VGPRs)
using f32x4   = __attribute__((ext_vector_type(4))) float;

__device__ __forceinline__ u16 f2bf(float f) {  // RTNE
    u32 x = __float_as_uint(f);
    x += 0x7fffu + ((x >> 16) & 1u);
    return (u16)(x >> 16);
}
__device__ __forceinline__ float bf2f(u16 u) {
    return __uint_as_float(((u32)u) << 16);
}

// --------------- fused prep + range-partitioned bucket scatter ------------
// Blocks [0, PREP_BLOCKS): x->bf16, W1/W2 -> bf16 transposed.
// Remaining blocks: 4 dst-range passes (pass-major block order). Per pass
// the dirty bucket-line working set is ~1.6 MB -> L2-resident, writes
// coalesce in L2 and retire once per line (R8: unpartitioned scatter wrote
// 72 MB to HBM = full-line amplification of 4B random writes).
__global__ void __launch_bounds__(256) k_prep_scatter(
        const float* __restrict__ x,
        const float* __restrict__ W1, const float* __restrict__ W2,
        u16* __restrict__ Xb, u16* __restrict__ Wb1, u16* __restrict__ Wb2,
        const int* __restrict__ src, const int* __restrict__ dst,
        int* __restrict__ cnt, int* __restrict__ col) {
    const int PREP_BLOCKS = (N_NODES_C * D_C / 4 + 255) / 256;  // 6250
    if (blockIdx.x < PREP_BLOCKS) {
        int i = blockIdx.x * 256 + threadIdx.x;
        int base = i * 4;
        if (base < N_NODES_C * D_C) {
            float4 f = *(const float4*)(x + base);
            ushort4 o;
            o.x = f2bf(f.x); o.y = f2bf(f.y); o.z = f2bf(f.z); o.w = f2bf(f.w);
            *(ushort4*)(Xb + base) = o;
        }
        if (i < 4096) {  // W[k][n] -> Wb[n][k]
            int n = i >> 6, k = i & 63;
            Wb1[i] = f2bf(W1[k * 64 + n]);
            Wb2[i] = f2bf(W2[k * 64 + n]);
        }
        return;
    }
    int bid = blockIdx.x - PREP_BLOCKS;
    int chunks = (gridDim.x - PREP_BLOCKS) / NPASS_C;
    int pass = bid / chunks;
    int chunk = bid - pass * chunks;
    const int RANGE = N_NODES_C / NPASS_C;  // 25000
    int lo = pass * RANGE;
    int hi = (pass == NPASS_C - 1) ? N_NODES_C : lo + RANGE;
    const int nquads = N_EDGES_C / 4;  // 300000
    int tid = chunk * 256 + threadIdx.x;
    int nthreads = chunks * 256;
    const int4* dst4 = (const int4*)dst;
    const int4* src4 = (const int4*)src;
    for (int i = tid; i < nquads; i += nthreads) {
        int4 d4 = dst4[i];
        int dd[4] = {d4.x, d4.y, d4.z, d4.w};
        bool in0 = dd[0] >= lo && dd[0] < hi;
        bool in1 = dd[1] >= lo && dd[1] < hi;
        bool in2 = dd[2] >= lo && dd[2] < hi;
        bool in3 = dd[3] >= lo && dd[3] < hi;
        if (in0 | in1 | in2 | in3) {
            int4 s4 = src4[i];
            int ss[4] = {s4.x, s4.y, s4.z, s4.w};
            bool in[4] = {in0, in1, in2, in3};
#pragma unroll
            for (int k = 0; k < 4; ++k) {
                if (in[k]) {
                    int pos = atomicAdd(&cnt[dd[k]], 1);
                    if (pos < CAP_C) col[(size_t)dd[k] * CAP_C + pos] = ss[k];
                }
            }
        }
    }
}

// ------------------- GEMM via MFMA 16x16x32 bf16 --------------------------
// One wave per 16-row strip. B fragments preloaded (constant across strips).
// Epilogue folds dinv[row] = rsqrt(cnt[row]+1).
__global__ void __launch_bounds__(256) k_gemm_mfma(
        const u16* __restrict__ Xb, const u16* __restrict__ Wb,
        const int* __restrict__ cnt, u16* __restrict__ T) {
    int lane = threadIdx.x & 63;
    int q = lane >> 4, ln = lane & 15;
    int wave = blockIdx.x * 4 + (threadIdx.x >> 6);
    int nwaves = gridDim.x * 4;
    frag_ab bfr[4][2];
#pragma unroll
    for (int nt = 0; nt < 4; ++nt)
#pragma unroll
        for (int kh = 0; kh < 2; ++kh)
            bfr[nt][kh] = *(const frag_ab*)(Wb + (nt * 16 + ln) * 64 + kh * 32 + q * 8);
    const int nstrips = N_NODES_C / 16;
    for (int s = wave; s < nstrips; s += nwaves) {
        int r0 = s * 16;
        frag_ab a0 = *(const frag_ab*)(Xb + (size_t)(r0 + ln) * 64 + q * 8);
        frag_ab a1 = *(const frag_ab*)(Xb + (size_t)(r0 + ln) * 64 + 32 + q * 8);
        f32x4 acc[4];
#pragma unroll
        for (int nt = 0; nt < 4; ++nt) {
            acc[nt] = (f32x4){0.f, 0.f, 0.f, 0.f};
            acc[nt] = __builtin_amdgcn_mfma_f32_16x16x32_bf16(a0, bfr[nt][0], acc[nt], 0, 0, 0);
            acc[nt] = __builtin_amdgcn_mfma_f32_16x16x32_bf16(a1, bfr[nt][1], acc[nt], 0, 0, 0);
        }
        float di[4];
#pragma unroll
        for (int reg = 0; reg < 4; ++reg)
            di[reg] = rsqrtf((float)(cnt[r0 + q * 4 + reg] + 1));
#pragma unroll
        for (int nt = 0; nt < 4; ++nt)
#pragma unroll
            for (int reg = 0; reg < 4; ++reg)
                T[(size_t)(r0 + q * 4 + reg) * 64 + nt * 16 + ln] =
                    f2bf(acc[nt][reg] * di[reg]);
    }
}

// ------------------- gather (pair-fused over buckets) ---------------------
// Wave owns a CONTIGUOUS chunk of node pairs; the pair's two buckets form
// one logical stream routed to accA/accB by boundary compare. 8-deep
// batches (proven VGPR~20 pipelined shape). Invalid slots -> hot self row.
// POOL: run-length pooling, ~1 atomic flush per lane per wave.
template <bool POOL>
__device__ __forceinline__ void gather_body(
        const u16* __restrict__ T, const int* __restrict__ col,
        const int* __restrict__ cnt,
        const float* __restrict__ b, const float* __restrict__ g,
        const float* __restrict__ be, const float* __restrict__ m,
        const float* __restrict__ v, const int* __restrict__ batch,
        u16* __restrict__ Ab, float* __restrict__ pooled) {
    int lane = threadIdx.x & 63;
    int wave = blockIdx.x * 4 + (threadIdx.x >> 6);
    int nwaves = gridDim.x * 4;
    float sc = g[lane] * rsqrtf(v[lane] + BN_EPS_C);
    float c0 = (b[lane] - m[lane]) * sc + be[lane];
    const int npairs = N_NODES_C / 2;
    const int chunk = (npairs + nwaves - 1) / nwaves;
    int p0 = wave * chunk;
    int p1 = p0 + chunk; if (p1 > npairs) p1 = npairs;
    float psum = 0.f; int curg = -1;
    for (int p = p0; p < p1; ++p) {
        int rA = __builtin_amdgcn_readfirstlane(p * 2);
        int rB = rA + 1;
        int degA = cnt[rA]; if (degA > CAP_C) degA = CAP_C;
        int degB = cnt[rB]; if (degB > CAP_C) degB = CAP_C;
        int tot = degA + degB;
        const int* cbA = col + (size_t)rA * CAP_C;
        const int* cbB = col + (size_t)rB * CAP_C;
        float accA = bf2f(T[(size_t)rA * 64 + lane]);  // self (dinv in T)
        float accB = bf2f(T[(size_t)rB * 64 + lane]);
        for (int j = 0; j < tot; j += 8) {
            int idx[8];
#pragma unroll
            for (int k = 0; k < 8; ++k) {
                int jj = j + k;
                bool valid = jj < tot;
                bool isB = jj >= degA;
                const int* cb = isB ? cbB : cbA;
                int o = isB ? (jj - degA) : jj;
                int c = cb[valid ? o : 0];   // in-bounds addr; value masked next
                idx[k] = valid ? c : rA;     // tail -> hot self row
            }
            float tv[8];
#pragma unroll
            for (int k = 0; k < 8; ++k)
                tv[k] = bf2f(T[(size_t)idx[k] * 64 + lane]);
#pragma unroll
            for (int k = 0; k < 8; ++k) {
                int jj = j + k;
                accA += (jj < degA) ? tv[k] : 0.f;
                accB += (jj >= degA && jj < tot) ? tv[k] : 0.f;
            }
        }
        float drA = rsqrtf((float)(degA + 1));
        float drB = rsqrtf((float)(degB + 1));
        float valA = fmaxf(fmaf(accA * drA, sc, c0), 0.f);
        float valB = fmaxf(fmaf(accB * drB, sc, c0), 0.f);
        if (POOL) {
            int gA = batch[rA], gB = batch[rB];
            if (gA != curg) {
                if (curg >= 0) atomicAdd(&pooled[curg * 64 + lane], psum);
                curg = gA; psum = 0.f;
            }
            psum += valA;
            if (gB != curg) {
                atomicAdd(&pooled[curg * 64 + lane], psum);
                curg = gB; psum = 0.f;
            }
            psum += valB;
        } else {
            Ab[(size_t)rA * 64 + lane] = f2bf(valA);
            Ab[(size_t)rB * 64 + lane] = f2bf(valB);
        }
    }
    if (POOL && curg >= 0) atomicAdd(&pooled[curg * 64 + lane], psum);
}

__global__ void __launch_bounds__(256) k_gather1(
        const u16* __restrict__ T, const int* __restrict__ col,
        const int* __restrict__ cnt,
        const float* __restrict__ b, const float* __restrict__ g,
        const float* __restrict__ be, const float* __restrict__ m,
        const float* __restrict__ v, u16* __restrict__ Ab) {
    gather_body<false>(T, col, cnt, b, g, be, m, v, nullptr, Ab, nullptr);
}

__global__ void __launch_bounds__(256) k_gather2(
        const u16* __restrict__ T, const int* __restrict__ col,
        const int* __restrict__ cnt,
        const float* __restrict__ b, const float* __restrict__ g,
        const float* __restrict__ be, const float* __restrict__ m,
        const float* __restrict__ v, const int* __restrict__ batch,
        float* __restrict__ pooled) {
    gather_body<true>(T, col, cnt, b, g, be, m, v, batch, nullptr, pooled);
}

// ----------------------------- classifier --------------------------------
__global__ void k_final(const float* __restrict__ pooled, const int* __restrict__ batch,
                        const float* __restrict__ Wc, const float* __restrict__ bc,
                        float* __restrict__ out) {
    __shared__ float sp[64 * 65];
    __shared__ int sub[64];
    int t = threadIdx.x;  // 256 threads
    for (int i = t; i < 4096; i += 256) sp[(i >> 6) * 65 + (i & 63)] = pooled[i];
    if (t < 64) {
        int lo = 0, hi = N_NODES_C;
        while (lo < hi) { int mid = (lo + hi) >> 1; if (batch[mid] > t) hi = mid; else lo = mid + 1; }
        sub[t] = lo;  // first index with batch > t
    }
    __syncthreads();
    if (t < 64) {
        int gi = t;
        int lb = gi ? sub[gi - 1] : 0;
        int cntg = sub[gi] - lb;
        float inv = 1.0f / fmaxf((float)cntg, 1.0f);
        float a0 = 0.f, a1 = 0.f;
#pragma unroll 8
        for (int f = 0; f < 64; ++f) {
            float p = sp[gi * 65 + f];
            a0 = fmaf(p, Wc[f * 2 + 0], a0);
            a1 = fmaf(p, Wc[f * 2 + 1], a1);
        }
        out[gi * 2 + 0] = a0 * inv + bc[0];
        out[gi * 2 + 1] = a1 * inv + bc[1];
    }
}

extern "C" void kernel_launch(void* const* d_in, const int* in_sizes, int n_in,
                              void* d_out, int out_size, void* d_ws, size_t ws_size,
                              hipStream_t stream) {
    const float* x    = (const float*)d_in[0];
    const int*   ei   = (const int*)d_in[1];
    const int*   batch= (const int*)d_in[2];
    const float* W1 = (const float*)d_in[3];
    const float* b1 = (const float*)d_in[4];
    const float* g1 = (const float*)d_in[5];
    const float* be1= (const float*)d_in[6];
    const float* m1 = (const float*)d_in[7];
    const float* v1 = (const float*)d_in[8];
    const float* W2 = (const float*)d_in[9];
    const float* b2 = (const float*)d_in[10];
    const float* g2 = (const float*)d_in[11];
    const float* be2= (const float*)d_in[12];
    const float* m2 = (const float*)d_in[13];
    const float* v2 = (const float*)d_in[14];
    const float* Wc = (const float*)d_in[15];
    const float* bc = (const float*)d_in[16];
    float* out = (float*)d_out;

    char* ws = (char*)d_ws;
    size_t off = 0;
    auto alloc = [&](size_t bytes) {
        size_t o = off;
        off = (off + bytes + 511) & ~(size_t)511;
        return o;
    };
    size_t o_cnt   = alloc((size_t)N_NODES_C * 4);
    size_t o_pool  = alloc((size_t)NUM_GRAPHS_C * D_C * 4);
    size_t zero_bytes = off;  // [cnt | pooled] zeroed each call
    size_t o_col   = alloc((size_t)N_NODES_C * CAP_C * 4);  // 25.6 MB buckets
    size_t o_xb    = alloc((size_t)N_NODES_C * D_C * 2);
    size_t o_wb1   = alloc(4096 * 2);
    size_t o_wb2   = alloc(4096 * 2);
    size_t o_t     = alloc((size_t)N_NODES_C * D_C * 2);  // bf16 (dinv folded)
    size_t o_ab    = alloc((size_t)N_NODES_C * D_C * 2);  // bf16 activations
    (void)ws_size; (void)in_sizes; (void)n_in; (void)out_size;

    int*   cnt    = (int*)(ws + o_cnt);
    float* pooled = (float*)(ws + o_pool);
    int*   col    = (int*)(ws + o_col);
    u16*   Xb     = (u16*)(ws + o_xb);
    u16*   Wb1    = (u16*)(ws + o_wb1);
    u16*   Wb2    = (u16*)(ws + o_wb2);
    u16*   T      = (u16*)(ws + o_t);
    u16*   Ab     = (u16*)(ws + o_ab);

    const int* srcp = ei;
    const int* dstp = ei + N_EDGES_C;

    hipMemsetAsync(ws, 0, zero_bytes, stream);

    const int PREP_BLOCKS = (N_NODES_C * D_C / 4 + 255) / 256;  // 6250
    const int SCHUNKS = 512;                                     // blocks per pass
    int psblocks = PREP_BLOCKS + SCHUNKS * NPASS_C;
    int gblocks = 2048;   // 8192 persistent waves
    int mblocks = 1563;   // 6252 waves: one 16-row strip each
    k_prep_scatter<<<psblocks, 256, 0, stream>>>(x, W1, W2, Xb, Wb1, Wb2,
                                                 srcp, dstp, cnt, col);

    k_gemm_mfma<<<mblocks, 256, 0, stream>>>(Xb, Wb1, cnt, T);
    k_gather1<<<gblocks, 256, 0, stream>>>(T, col, cnt, b1, g1, be1, m1, v1, Ab);
    k_gemm_mfma<<<mblocks, 256, 0, stream>>>(Ab, Wb2, cnt, T);
    k_gather2<<<gblocks, 256, 0, stream>>>(T, col, cnt, b2, g2, be2, m2, v2,
                                           batch, pooled);
    k_final<<<1, 256, 0, stream>>>(pooled, batch, Wc, bc, out);
}

// Round 10
// 374.446 us; speedup vs baseline: 1.1179x; 1.0789x over previous
//
#include <hip/hip_runtime.h>

#define N_NODES_C 100000
#define N_EDGES_C 1200000
#define NUM_GRAPHS_C 64
#define D_C 64
#define CAP_C 64
#define NPASS_C 8
#define BN_EPS_C 1e-5f

typedef unsigned short u16;
typedef unsigned int u32;

using frag_ab = __attribute__((ext_vector_type(8))) short;  // 8 bf16 (4 VGPRs)
using f32x4   = __attribute__((ext_vector_type(4))) float;

__device__ __forceinline__ u16 f2bf(float f) {  // RTNE
    u32 x = __float_as_uint(f);
    x += 0x7fffu + ((x >> 16) & 1u);
    return (u16)(x >> 16);
}
__device__ __forceinline__ float bf2f(u16 u) {
    return __uint_as_float(((u32)u) << 16);
}

// ------------------- prep: x -> bf16, W1/W2 -> bf16 [n][k] ----------------
__global__ void k_prep(const float* __restrict__ x,
                       const float* __restrict__ W1, const float* __restrict__ W2,
                       u16* __restrict__ Xb, u16* __restrict__ Wb1,
                       u16* __restrict__ Wb2) {
    int i = blockIdx.x * 256 + threadIdx.x;
    int base = i * 4;
    if (base < N_NODES_C * D_C) {
        float4 f = *(const float4*)(x + base);
        ushort4 o;
        o.x = f2bf(f.x); o.y = f2bf(f.y); o.z = f2bf(f.z); o.w = f2bf(f.w);
        *(ushort4*)(Xb + base) = o;
    }
    if (i < 4096) {  // W[k][n] -> Wb[n][k]
        int n = i >> 6, k = i & 63;
        Wb1[i] = f2bf(W1[k * 64 + n]);
        Wb2[i] = f2bf(W2[k * 64 + n]);
    }
}

// ------------------- XCD-swizzled bucket scatter --------------------------
// pass = blockIdx & 7: blocks land on XCDs round-robin, so all blocks
// owning dst-range `pass` share one XCD -> that range's dirty bucket lines
// (~1.6 MB) stay in the XCD-private 4 MB L2 and retire to HBM once, instead
// of the 72 MB full-line amplification measured in R8/R9 (temporal passes
// failed: all resident concurrently). Every XCD re-reads the 9.6 MB edge
// stream from LLC — trading cheap reads for expensive writes.
__global__ void __launch_bounds__(256) k_scatter(
        const int* __restrict__ src, const int* __restrict__ dst,
        int* __restrict__ cnt, int* __restrict__ col) {
    int pass = blockIdx.x & (NPASS_C - 1);
    int chunk = blockIdx.x >> 3;
    int nchunks = gridDim.x >> 3;
    const int RANGE = N_NODES_C / NPASS_C;  // 12500
    int lo = pass * RANGE;
    int hi = (pass == NPASS_C - 1) ? N_NODES_C : lo + RANGE;
    const int nquads = N_EDGES_C / 4;  // 300000
    int tid = chunk * 256 + threadIdx.x;
    int nthreads = nchunks * 256;
    const int4* dst4 = (const int4*)dst;
    const int4* src4 = (const int4*)src;
    for (int i = tid; i < nquads; i += nthreads) {
        int4 d4 = dst4[i];
        int dd[4] = {d4.x, d4.y, d4.z, d4.w};
        bool in0 = dd[0] >= lo && dd[0] < hi;
        bool in1 = dd[1] >= lo && dd[1] < hi;
        bool in2 = dd[2] >= lo && dd[2] < hi;
        bool in3 = dd[3] >= lo && dd[3] < hi;
        if (in0 | in1 | in2 | in3) {
            int4 s4 = src4[i];
            int ss[4] = {s4.x, s4.y, s4.z, s4.w};
            bool in[4] = {in0, in1, in2, in3};
#pragma unroll
            for (int k = 0; k < 4; ++k) {
                if (in[k]) {
                    int pos = atomicAdd(&cnt[dd[k]], 1);
                    if (pos < CAP_C) col[(size_t)dd[k] * CAP_C + pos] = ss[k];
                }
            }
        }
    }
}

// ------------------- GEMM via MFMA 16x16x32 bf16 --------------------------
// One wave per 16-row strip. B fragments preloaded (constant across strips).
// Epilogue folds dinv[row] = rsqrt(cnt[row]+1).
__global__ void __launch_bounds__(256) k_gemm_mfma(
        const u16* __restrict__ Xb, const u16* __restrict__ Wb,
        const int* __restrict__ cnt, u16* __restrict__ T) {
    int lane = threadIdx.x & 63;
    int q = lane >> 4, ln = lane & 15;
    int wave = blockIdx.x * 4 + (threadIdx.x >> 6);
    int nwaves = gridDim.x * 4;
    frag_ab bfr[4][2];
#pragma unroll
    for (int nt = 0; nt < 4; ++nt)
#pragma unroll
        for (int kh = 0; kh < 2; ++kh)
            bfr[nt][kh] = *(const frag_ab*)(Wb + (nt * 16 + ln) * 64 + kh * 32 + q * 8);
    const int nstrips = N_NODES_C / 16;
    for (int s = wave; s < nstrips; s += nwaves) {
        int r0 = s * 16;
        frag_ab a0 = *(const frag_ab*)(Xb + (size_t)(r0 + ln) * 64 + q * 8);
        frag_ab a1 = *(const frag_ab*)(Xb + (size_t)(r0 + ln) * 64 + 32 + q * 8);
        f32x4 acc[4];
#pragma unroll
        for (int nt = 0; nt < 4; ++nt) {
            acc[nt] = (f32x4){0.f, 0.f, 0.f, 0.f};
            acc[nt] = __builtin_amdgcn_mfma_f32_16x16x32_bf16(a0, bfr[nt][0], acc[nt], 0, 0, 0);
            acc[nt] = __builtin_amdgcn_mfma_f32_16x16x32_bf16(a1, bfr[nt][1], acc[nt], 0, 0, 0);
        }
        float di[4];
#pragma unroll
        for (int reg = 0; reg < 4; ++reg)
            di[reg] = rsqrtf((float)(cnt[r0 + q * 4 + reg] + 1));
#pragma unroll
        for (int nt = 0; nt < 4; ++nt)
#pragma unroll
            for (int reg = 0; reg < 4; ++reg)
                T[(size_t)(r0 + q * 4 + reg) * 64 + nt * 16 + ln] =
                    f2bf(acc[nt][reg] * di[reg]);
    }
}

// ------------------- gather (pair-fused over buckets) ---------------------
// Wave owns a CONTIGUOUS chunk of node pairs; the pair's two buckets form
// one logical stream routed to accA/accB by boundary compare. 8-deep
// batches (proven VGPR~20 pipelined shape). Invalid slots -> hot self row.
// POOL: run-length pooling, ~1 atomic flush per lane per wave.
template <bool POOL>
__device__ __forceinline__ void gather_body(
        const u16* __restrict__ T, const int* __restrict__ col,
        const int* __restrict__ cnt,
        const float* __restrict__ b, const float* __restrict__ g,
        const float* __restrict__ be, const float* __restrict__ m,
        const float* __restrict__ v, const int* __restrict__ batch,
        u16* __restrict__ Ab, float* __restrict__ pooled) {
    int lane = threadIdx.x & 63;
    int wave = blockIdx.x * 4 + (threadIdx.x >> 6);
    int nwaves = gridDim.x * 4;
    float sc = g[lane] * rsqrtf(v[lane] + BN_EPS_C);
    float c0 = (b[lane] - m[lane]) * sc + be[lane];
    const int npairs = N_NODES_C / 2;
    const int chunk = (npairs + nwaves - 1) / nwaves;
    int p0 = wave * chunk;
    int p1 = p0 + chunk; if (p1 > npairs) p1 = npairs;
    float psum = 0.f; int curg = -1;
    for (int p = p0; p < p1; ++p) {
        int rA = __builtin_amdgcn_readfirstlane(p * 2);
        int rB = rA + 1;
        int degA = cnt[rA]; if (degA > CAP_C) degA = CAP_C;
        int degB = cnt[rB]; if (degB > CAP_C) degB = CAP_C;
        int tot = degA + degB;
        const int* cbA = col + (size_t)rA * CAP_C;
        const int* cbB = col + (size_t)rB * CAP_C;
        float accA = bf2f(T[(size_t)rA * 64 + lane]);  // self (dinv in T)
        float accB = bf2f(T[(size_t)rB * 64 + lane]);
        for (int j = 0; j < tot; j += 8) {
            int idx[8];
#pragma unroll
            for (int k = 0; k < 8; ++k) {
                int jj = j + k;
                bool valid = jj < tot;
                bool isB = jj >= degA;
                const int* cb = isB ? cbB : cbA;
                int o = isB ? (jj - degA) : jj;
                int c = cb[valid ? o : 0];   // in-bounds addr; value masked next
                idx[k] = valid ? c : rA;     // tail -> hot self row
            }
            float tv[8];
#pragma unroll
            for (int k = 0; k < 8; ++k)
                tv[k] = bf2f(T[(size_t)idx[k] * 64 + lane]);
#pragma unroll
            for (int k = 0; k < 8; ++k) {
                int jj = j + k;
                accA += (jj < degA) ? tv[k] : 0.f;
                accB += (jj >= degA && jj < tot) ? tv[k] : 0.f;
            }
        }
        float drA = rsqrtf((float)(degA + 1));
        float drB = rsqrtf((float)(degB + 1));
        float valA = fmaxf(fmaf(accA * drA, sc, c0), 0.f);
        float valB = fmaxf(fmaf(accB * drB, sc, c0), 0.f);
        if (POOL) {
            int gA = batch[rA], gB = batch[rB];
            if (gA != curg) {
                if (curg >= 0) atomicAdd(&pooled[curg * 64 + lane], psum);
                curg = gA; psum = 0.f;
            }
            psum += valA;
            if (gB != curg) {
                atomicAdd(&pooled[curg * 64 + lane], psum);
                curg = gB; psum = 0.f;
            }
            psum += valB;
        } else {
            Ab[(size_t)rA * 64 + lane] = f2bf(valA);
            Ab[(size_t)rB * 64 + lane] = f2bf(valB);
        }
    }
    if (POOL && curg >= 0) atomicAdd(&pooled[curg * 64 + lane], psum);
}

__global__ void __launch_bounds__(256) k_gather1(
        const u16* __restrict__ T, const int* __restrict__ col,
        const int* __restrict__ cnt,
        const float* __restrict__ b, const float* __restrict__ g,
        const float* __restrict__ be, const float* __restrict__ m,
        const float* __restrict__ v, u16* __restrict__ Ab) {
    gather_body<false>(T, col, cnt, b, g, be, m, v, nullptr, Ab, nullptr);
}

__global__ void __launch_bounds__(256) k_gather2(
        const u16* __restrict__ T, const int* __restrict__ col,
        const int* __restrict__ cnt,
        const float* __restrict__ b, const float* __restrict__ g,
        const float* __restrict__ be, const float* __restrict__ m,
        const float* __restrict__ v, const int* __restrict__ batch,
        float* __restrict__ pooled) {
    gather_body<true>(T, col, cnt, b, g, be, m, v, batch, nullptr, pooled);
}

// ----------------------------- classifier --------------------------------
__global__ void k_final(const float* __restrict__ pooled, const int* __restrict__ batch,
                        const float* __restrict__ Wc, const float* __restrict__ bc,
                        float* __restrict__ out) {
    __shared__ float sp[64 * 65];
    __shared__ int sub[64];
    int t = threadIdx.x;  // 256 threads
    for (int i = t; i < 4096; i += 256) sp[(i >> 6) * 65 + (i & 63)] = pooled[i];
    if (t < 64) {
        int lo = 0, hi = N_NODES_C;
        while (lo < hi) { int mid = (lo + hi) >> 1; if (batch[mid] > t) hi = mid; else lo = mid + 1; }
        sub[t] = lo;  // first index with batch > t
    }
    __syncthreads();
    if (t < 64) {
        int gi = t;
        int lb = gi ? sub[gi - 1] : 0;
        int cntg = sub[gi] - lb;
        float inv = 1.0f / fmaxf((float)cntg, 1.0f);
        float a0 = 0.f, a1 = 0.f;
#pragma unroll 8
        for (int f = 0; f < 64; ++f) {
            float p = sp[gi * 65 + f];
            a0 = fmaf(p, Wc[f * 2 + 0], a0);
            a1 = fmaf(p, Wc[f * 2 + 1], a1);
        }
        out[gi * 2 + 0] = a0 * inv + bc[0];
        out[gi * 2 + 1] = a1 * inv + bc[1];
    }
}

extern "C" void kernel_launch(void* const* d_in, const int* in_sizes, int n_in,
                              void* d_out, int out_size, void* d_ws, size_t ws_size,
                              hipStream_t stream) {
    const float* x    = (const float*)d_in[0];
    const int*   ei   = (const int*)d_in[1];
    const int*   batch= (const int*)d_in[2];
    const float* W1 = (const float*)d_in[3];
    const float* b1 = (const float*)d_in[4];
    const float* g1 = (const float*)d_in[5];
    const float* be1= (const float*)d_in[6];
    const float* m1 = (const float*)d_in[7];
    const float* v1 = (const float*)d_in[8];
    const float* W2 = (const float*)d_in[9];
    const float* b2 = (const float*)d_in[10];
    const float* g2 = (const float*)d_in[11];
    const float* be2= (const float*)d_in[12];
    const float* m2 = (const float*)d_in[13];
    const float* v2 = (const float*)d_in[14];
    const float* Wc = (const float*)d_in[15];
    const float* bc = (const float*)d_in[16];
    float* out = (float*)d_out;

    char* ws = (char*)d_ws;
    size_t off = 0;
    auto alloc = [&](size_t bytes) {
        size_t o = off;
        off = (off + bytes + 511) & ~(size_t)511;
        return o;
    };
    size_t o_cnt   = alloc((size_t)N_NODES_C * 4);
    size_t o_pool  = alloc((size_t)NUM_GRAPHS_C * D_C * 4);
    size_t zero_bytes = off;  // [cnt | pooled] zeroed each call
    size_t o_col   = alloc((size_t)N_NODES_C * CAP_C * 4);  // 25.6 MB buckets
    size_t o_xb    = alloc((size_t)N_NODES_C * D_C * 2);
    size_t o_wb1   = alloc(4096 * 2);
    size_t o_wb2   = alloc(4096 * 2);
    size_t o_t     = alloc((size_t)N_NODES_C * D_C * 2);  // bf16 (dinv folded)
    size_t o_ab    = alloc((size_t)N_NODES_C * D_C * 2);  // bf16 activations
    (void)ws_size; (void)in_sizes; (void)n_in; (void)out_size;

    int*   cnt    = (int*)(ws + o_cnt);
    float* pooled = (float*)(ws + o_pool);
    int*   col    = (int*)(ws + o_col);
    u16*   Xb     = (u16*)(ws + o_xb);
    u16*   Wb1    = (u16*)(ws + o_wb1);
    u16*   Wb2    = (u16*)(ws + o_wb2);
    u16*   T      = (u16*)(ws + o_t);
    u16*   Ab     = (u16*)(ws + o_ab);

    const int* srcp = ei;
    const int* dstp = ei + N_EDGES_C;

    hipMemsetAsync(ws, 0, zero_bytes, stream);

    int pblocks = (N_NODES_C * D_C / 4 + 255) / 256;  // 6250
    int sblocks = 2048;   // 256 chunks x 8 XCD-swizzled ranges
    int gblocks = 2048;   // 8192 persistent waves
    int mblocks = 1563;   // 6252 waves: one 16-row strip each
    k_prep<<<pblocks, 256, 0, stream>>>(x, W1, W2, Xb, Wb1, Wb2);
    k_scatter<<<sblocks, 256, 0, stream>>>(srcp, dstp, cnt, col);

    k_gemm_mfma<<<mblocks, 256, 0, stream>>>(Xb, Wb1, cnt, T);
    k_gather1<<<gblocks, 256, 0, stream>>>(T, col, cnt, b1, g1, be1, m1, v1, Ab);
    k_gemm_mfma<<<mblocks, 256, 0, stream>>>(Ab, Wb2, cnt, T);
    k_gather2<<<gblocks, 256, 0, stream>>>(T, col, cnt, b2, g2, be2, m2, v2,
                                           batch, pooled);
    k_final<<<1, 256, 0, stream>>>(pooled, batch, Wc, bc, out);
}